// Round 2
// baseline (147.138 us; speedup 1.0000x reference)
//
#include <hip/hip_runtime.h>

// Problem constants (fixed by setup_inputs)
constexpr int N_    = 4;
constexpr int C_    = 151;
constexpr int HW_   = 512 * 512;          // 262144
constexpr int NPIX_ = N_ * HW_;           // 1048576
constexpr int QUADS_ = NPIX_ / 4;         // 262144
constexpr int NBLK_  = QUADS_ / 256;      // 1024
constexpr int OLD_CL_ = 100;
constexpr int IGNORE_ = 255;

typedef float v4f __attribute__((ext_vector_type(4)));
typedef int   v4i __attribute__((ext_vector_type(4)));

struct Ws {
    double       acc;
    unsigned int cnt;
};

__global__ __launch_bounds__(256)
void wce_main(const float* __restrict__ inputs,
              const int*   __restrict__ targets,
              const float* __restrict__ probs,
              Ws*          __restrict__ ws,
              float*       __restrict__ out) {
    const int q    = blockIdx.x * 256 + threadIdx.x;   // quad-pixel index
    const int pix0 = q * 4;
    const int n    = pix0 / HW_;
    const int hw   = pix0 - n * HW_;
    const float* inp = inputs + (size_t)n * C_ * HW_ + hw;

    // targets for the 4 pixels (streaming, no reuse)
    const v4i t4 = __builtin_nontemporal_load(
        reinterpret_cast<const v4i*>(targets + pix0));
    int t[4] = {t4.x, t4.y, t4.z, t4.w};
    int lab2c[4];
#pragma unroll
    for (int j = 0; j < 4; ++j) {
        int l = (t[j] < OLD_CL_) ? 0 : t[j];       // lab2 (255 stays 255)
        lab2c[j] = (l > C_ - 1) ? (C_ - 1) : l;    // clip to C-1
    }

    float s[4], s100[4], e0[4], x0v[4], g[4];

    // --- channel 0 (peeled) ---
    {
        v4f x4 = __builtin_nontemporal_load(reinterpret_cast<const v4f*>(inp));
#pragma unroll
        for (int j = 0; j < 4; ++j) {
            x0v[j] = x4[j];
            e0[j]  = __expf(x4[j]);
            s[j]   = e0[j];
            g[j]   = x4[j];   // only consumed when lab2c==0 path is not taken
        }
    }
    // --- channels 1..99 ---
#pragma unroll 4
    for (int c = 1; c < OLD_CL_; ++c) {
        v4f x4 = __builtin_nontemporal_load(
            reinterpret_cast<const v4f*>(inp + (size_t)c * HW_));
#pragma unroll
        for (int j = 0; j < 4; ++j) {
            s[j] += __expf(x4[j]);
            g[j] = (c == lab2c[j]) ? x4[j] : g[j];
        }
    }
    float local = 0.f;
#pragma unroll
    for (int j = 0; j < 4; ++j) s100[j] = s[j];  // sum(exp) over channels [0,100)
    // --- channels 100..150 ---
#pragma unroll 4
    for (int c = OLD_CL_; c < C_; ++c) {
        v4f x4 = __builtin_nontemporal_load(
            reinterpret_cast<const v4f*>(inp + (size_t)c * HW_));
#pragma unroll
        for (int j = 0; j < 4; ++j) {
            s[j] += __expf(x4[j]);
            g[j] = (c == lab2c[j]) ? x4[j] : g[j];
        }
    }

    // seen/not-seen probs: [N,2,H,W] (streaming)
    const float* pp = probs + (size_t)n * 2 * HW_ + hw;
    const v4f pa = __builtin_nontemporal_load(reinterpret_cast<const v4f*>(pp));
    const v4f pb = __builtin_nontemporal_load(reinterpret_cast<const v4f*>(pp + HW_));

#pragma unroll
    for (int j = 0; j < 4; ++j) {
        const float den    = __logf(s[j]);
        const float out_bg = x0v[j] - den;
        const float out_fg = __logf(s[j] - e0[j]) - den;
        const float out0n  = __logf(s100[j]) - den;

        const bool valid = (t[j] != IGNORE_);
        const int  mt    = valid ? t[j] : 0;

        float msn = fmaxf(pa[j], pb[j]);
        msn = (msn > 0.5f) ? 1.0f : msn;
        const float w     = (mt == 0) ? msn : 0.f;
        const float f1    = 1.f - w;
        const float focal = f1 * f1;
        const float picked = (mt == 0) ? out_bg : out_fg;
        const float l1 = valid ? (-focal * picked) : 0.f;

        const int  lab2   = (t[j] < OLD_CL_) ? 0 : t[j];
        const bool valid2 = (lab2 != IGNORE_);
        const float val = (lab2c[j] == 0) ? out0n : (g[j] - den);
        const float l2  = valid2 ? (-val) : 0.f;

        local += l1 + l2;
    }

    // block reduction: wave64 shuffle -> LDS -> one double atomic per block
    double d = (double)local;
#pragma unroll
    for (int off = 32; off >= 1; off >>= 1)
        d += __shfl_down(d, off, 64);

    __shared__ double lds[4];
    const int lane = threadIdx.x & 63;
    const int wid  = threadIdx.x >> 6;
    if (lane == 0) lds[wid] = d;
    __syncthreads();
    if (threadIdx.x == 0) {
        const double bsum = lds[0] + lds[1] + lds[2] + lds[3];
        atomicAdd(&ws->acc, bsum);               // device-scope
        __threadfence();
        const unsigned int old = atomicAdd(&ws->cnt, 1u);
        if (old == (unsigned int)(gridDim.x - 1)) {
            // last block: all other blocks' acc-adds are visible (fence+atomic)
            const double tot = atomicAdd(&ws->acc, 0.0);  // coherent read
            out[0] = (float)(tot / (double)NPIX_);
        }
    }
}

extern "C" void kernel_launch(void* const* d_in, const int* in_sizes, int n_in,
                              void* d_out, int out_size, void* d_ws, size_t ws_size,
                              hipStream_t stream) {
    const float* inputs  = (const float*)d_in[0];
    const int*   targets = (const int*)  d_in[1];
    const float* probs   = (const float*)d_in[2];
    // d_in[3] = task_num (unused by the math)
    float* out = (float*)d_out;
    Ws*    ws  = (Ws*)d_ws;

    // acc and cnt must be zero at kernel start on EVERY call (ws is not
    // re-poisoned/restored between timed replays).
    hipMemsetAsync(ws, 0, sizeof(Ws), stream);
    wce_main<<<NBLK_, 256, 0, stream>>>(inputs, targets, probs, ws, out);
}